// Round 1
// baseline (14275.488 us; speedup 1.0000x reference)
//
#include <hip/hip_runtime.h>
#include <math.h>

#pragma clang fp contract(off)

#define BB 64      // batch
#define N_IN 64
#define N_E 256
#define N_I 64
#define N_OUT 10

__device__ inline unsigned long long rfl64(unsigned long long x) {
  unsigned int lo = __builtin_amdgcn_readfirstlane((unsigned int)(x & 0xffffffffull));
  unsigned int hi = __builtin_amdgcn_readfirstlane((unsigned int)(x >> 32));
  return (((unsigned long long)hi) << 32) | (unsigned long long)lo;
}

// Sparse gather over two masks at once: sums w[j*str+col] over set bits of m
// (ascending j). Up to GA+GB loads issued per iteration for latency overlap.
template<int GA, int GB, bool CLA>
__device__ inline void gather_dual(unsigned long long mA, const float* __restrict__ wA, int strA, int colA,
                                   unsigned long long mB, const float* __restrict__ wB, int strB, int colB,
                                   float& outA, float& outB) {
  float accA = 0.f, accB = 0.f;
  while (mA | mB) {
    int ja[GA]; bool va[GA];
    int jb[GB]; bool vb[GB];
#pragma unroll
    for (int k = 0; k < GA; ++k) {
      va[k] = (mA != 0ull);
      ja[k] = va[k] ? (__ffsll((unsigned long long)mA) - 1) : 0;
      mA &= (mA - 1ull);
    }
#pragma unroll
    for (int k = 0; k < GB; ++k) {
      vb[k] = (mB != 0ull);
      jb[k] = vb[k] ? (__ffsll((unsigned long long)mB) - 1) : 0;
      mB &= (mB - 1ull);
    }
    float fa[GA], fb[GB];
#pragma unroll
    for (int k = 0; k < GA; ++k) {
      float x = wA[ja[k] * strA + colA];
      fa[k] = CLA ? fmaxf(x, 0.f) : x;
    }
#pragma unroll
    for (int k = 0; k < GB; ++k) fb[k] = wB[jb[k] * strB + colB];
#pragma unroll
    for (int k = 0; k < GA; ++k) accA += va[k] ? fa[k] : 0.f;
#pragma unroll
    for (int k = 0; k < GB; ++k) accB += vb[k] ? fb[k] : 0.f;
  }
  outA = accA; outB = accB;
}

template<int G>
__device__ inline float gather1(unsigned long long m, const float* __restrict__ w, int str, int col) {
  float acc = 0.f;
  while (m) {
    int j[G]; bool v[G];
#pragma unroll
    for (int k = 0; k < G; ++k) {
      v[k] = (m != 0ull);
      j[k] = v[k] ? (__ffsll((unsigned long long)m) - 1) : 0;
      m &= (m - 1ull);
    }
    float f[G];
#pragma unroll
    for (int k = 0; k < G; ++k) f[k] = w[j[k] * str + col];
#pragma unroll
    for (int k = 0; k < G; ++k) acc += v[k] ? f[k] : 0.f;
  }
  return acc;
}

// 256-bit (4-word) mask gather, ascending global row order.
template<bool CL>
__device__ inline float gather256(const unsigned long long* m4, const float* __restrict__ w, int str, int col) {
  unsigned long long m0 = m4[0], m1 = m4[1], m2 = m4[2], m3 = m4[3];
  float acc = 0.f;
  while (m0 | m1 | m2 | m3) {
    int j[8]; bool v[8];
#pragma unroll
    for (int k = 0; k < 8; ++k) {
      bool h0 = (m0 != 0ull), h1 = (m1 != 0ull), h2 = (m2 != 0ull), h3 = (m3 != 0ull);
      int idx = 0;
      if (h0)      { idx = __ffsll((unsigned long long)m0) - 1;       m0 &= (m0 - 1ull); }
      else if (h1) { idx = 64 + __ffsll((unsigned long long)m1) - 1;  m1 &= (m1 - 1ull); }
      else if (h2) { idx = 128 + __ffsll((unsigned long long)m2) - 1; m2 &= (m2 - 1ull); }
      else if (h3) { idx = 192 + __ffsll((unsigned long long)m3) - 1; m3 &= (m3 - 1ull); }
      v[k] = h0 | h1 | h2 | h3;
      j[k] = idx;
    }
    float f[8];
#pragma unroll
    for (int k = 0; k < 8; ++k) {
      float x = w[j[k] * str + col];
      f[k] = CL ? fmaxf(x, 0.f) : x;
    }
#pragma unroll
    for (int k = 0; k < 8; ++k) acc += v[k] ? f[k] : 0.f;
  }
  return acc;
}

__global__ __launch_bounds__(256) void ping_kernel(
    const float* __restrict__ g_in,   // [T,64,64]
    const float* __restrict__ g_W0,   // [64,256]  (clamp >=0 at use)
    const float* __restrict__ g_W1,   // [256,10]  (clamp >=0 at stage)
    const float* __restrict__ g_Wee,  // [256,256]
    const float* __restrict__ g_Wei,  // [256,64]
    const float* __restrict__ g_Wie,  // [64,256]
    float* __restrict__ g_out,        // [64,10]
    int T, float dA, float dG)
{
  const int tid  = threadIdx.x;
  const int lane = tid & 63;
  const int wav  = tid >> 6;
  const int b    = blockIdx.x;

  __shared__ unsigned long long sh_mE[2][4];  // double-buffered E spike masks
  __shared__ unsigned long long sh_mI[2];     // double-buffered I spike masks
  __shared__ float sh_part[4][64];            // E->I gather partials (word w, I neuron i)
  __shared__ int   sh_wee;                    // 1 if W_ee has any nonzero
  __shared__ float sh_W1[N_E * N_OUT];        // clamped W1 (10 KB)

  if (tid < 4) { sh_mE[0][tid] = 0ull; sh_mE[1][tid] = 0ull; }
  if (tid == 0) { sh_mI[0] = 0ull; sh_mI[1] = 0ull; sh_wee = 0; }
  for (int k = tid; k < N_E * N_OUT; k += 256) sh_W1[k] = fmaxf(g_W1[k], 0.f);
  __syncthreads();

  // Detect all-zero W_ee (true for this data): skipping it is fp-exact since
  // reference adds an exactly-zero matmul result.
  bool any = false;
  for (int k = 0; k < N_E; ++k) any |= (g_Wee[k * N_E + tid] != 0.f);
  if (__ballot(any) != 0ull && lane == 0) sh_wee = 1;
  __syncthreads();
  const int wee = sh_wee;

  // E state (all 256 threads: E neuron = tid)
  float v_e = -65.f, ge = 0.f, gi = 0.f; int rf_e = 0;
  // I state (wave 1: I neuron = lane)
  float v_i = -65.f, gei = 0.f; int rf_i = 0;
  // output state (wave 2, lanes < 10)
  float v_o = -65.f, go = 0.f, acc = 0.f; int rf_o = 0;

  int par = 0;
  float cur = g_in[b * N_IN + lane];   // input spike for t=0 (each wave redundantly)
  for (int t = 0; t < T; ++t) {
    int tn = (t + 1 < T) ? (t + 1) : (T - 1);
    float nxt = g_in[(tn * BB + b) * N_IN + lane];   // prefetch next step

    unsigned long long mIn = __ballot(cur != 0.f);         // input spikes (wave-local ballot)
    unsigned long long mIp = rfl64(sh_mI[par]);            // prev I spikes
    unsigned long long mEw = rfl64(sh_mE[par][wav]);       // prev E spikes, word `wav`

    // ge kick (input @ W0, clamped) and gi kick (I @ W_ie), loads co-issued
    float kin, kie;
    gather_dual<4, 4, true>(mIn, g_W0, N_E, tid, mIp, g_Wie, N_E, tid, kin, kie);

    // E->I partial: this wave handles 64-bit word `wav` of prev E mask, I neuron = lane
    sh_part[wav][lane] = gather1<8>(mEw, g_Wei + (wav * 64) * N_I, N_I, lane);

    float kee = 0.f;
    if (wee) {
      unsigned long long me[4];
      me[0] = rfl64(sh_mE[par][0]); me[1] = rfl64(sh_mE[par][1]);
      me[2] = rfl64(sh_mE[par][2]); me[3] = rfl64(sh_mE[par][3]);
      kee = gather256<false>(me, g_Wee, N_E, tid);
    }

    // exp_synapse: kick then decay (order matches reference exactly)
    ge = ((ge + kin) + kee) * dA;
    gi = (gi + kie) * dG;

    // E LIF (COBA, C_m=1, g_L=0.05, ref=12) — op order mirrors numpy, no FMA contraction
    {
      float t2 = ge * (0.f - v_e);
      float t3 = gi * (-80.f - v_e);
      float Itot = t2 + t3;
      float dv = 0.25f * ((-0.05f) * (v_e - (-65.f)) + Itot);
      dv = dv * 0.0125f + dv * 0.9875f;       // _scale_grad forward (not identity in fp!)
      v_e = fmaxf(v_e + dv, -200.f);
      rf_e = rf_e - 1; if (rf_e < 0) rf_e = 0;
      bool can = (rf_e == 0);
      bool sE = ((v_e - (-50.f)) >= 0.f) && can;
      v_e = (sE || !can) ? -65.f : v_e;
      rf_e = sE ? 12 : rf_e;
      unsigned long long balE = __ballot(sE);
      if (lane == 0) sh_mE[par ^ 1][wav] = balE;
    }

    __syncthreads();   // barrier 1: fresh E masks + partials visible

    if (wav == 1) {
      // I LIF (C_m=0.5, g_L=0.1, ref=6)
      float p = ((sh_part[0][lane] + sh_part[1][lane]) + sh_part[2][lane]) + sh_part[3][lane];
      gei = (gei + p) * dA;
      float Ii = gei * (0.f - v_i);
      float dvi = 0.5f * ((-0.1f) * (v_i - (-65.f)) + Ii);
      dvi = dvi * 0.0125f + dvi * 0.9875f;
      v_i = fmaxf(v_i + dvi, -200.f);
      rf_i = rf_i - 1; if (rf_i < 0) rf_i = 0;
      bool canI = (rf_i == 0);
      bool sI = ((v_i - (-50.f)) >= 0.f) && canI;
      v_i = (sI || !canI) ? -65.f : v_i;
      rf_i = sI ? 6 : rf_i;
      unsigned long long balI = __ballot(sI);
      if (lane == 0) sh_mI[par ^ 1] = balI;
    } else if (wav == 2) {
      // output layer driven by FRESH E spikes
      unsigned long long me[4];
      me[0] = rfl64(sh_mE[par ^ 1][0]); me[1] = rfl64(sh_mE[par ^ 1][1]);
      me[2] = rfl64(sh_mE[par ^ 1][2]); me[3] = rfl64(sh_mE[par ^ 1][3]);
      int col = (lane < N_OUT) ? lane : 0;
      float ko = gather256<false>(me, sh_W1, N_OUT, col);
      if (lane < N_OUT) {
        go = (go + ko) * dA;
        float Io = go * (0.f - v_o);
        float dvo = 0.25f * ((-0.05f) * (v_o - (-65.f)) + Io);
        dvo = dvo * 0.0125f + dvo * 0.9875f;
        v_o = fmaxf(v_o + dvo, -200.f);
        rf_o = rf_o - 1; if (rf_o < 0) rf_o = 0;
        bool canO = (rf_o == 0);
        bool sO = ((v_o - (-50.f)) >= 0.f) && canO;
        v_o = (sO || !canO) ? -65.f : v_o;
        rf_o = sO ? 12 : rf_o;
        acc += sO ? 1.f : 0.f;
      }
    }
    __syncthreads();   // barrier 2: protect maskI write + partial buffer reuse
    par ^= 1;
    cur = nxt;
  }

  if (wav == 2 && lane < N_OUT) g_out[b * N_OUT + lane] = acc;
}

extern "C" void kernel_launch(void* const* d_in, const int* in_sizes, int n_in,
                              void* d_out, int out_size, void* d_ws, size_t ws_size,
                              hipStream_t stream) {
  const float* g_in  = (const float*)d_in[0];
  const float* g_W0  = (const float*)d_in[1];
  const float* g_W1  = (const float*)d_in[2];
  const float* g_Wee = (const float*)d_in[3];
  const float* g_Wei = (const float*)d_in[4];
  const float* g_Wie = (const float*)d_in[5];
  float* out = (float*)d_out;
  int T = in_sizes[0] / (BB * N_IN);
  float dA = (float)exp(-0.25 / 2.0);   // tau_ampa = 2.0
  float dG = (float)exp(-0.25 / 9.0);   // tau_gaba = 9.0
  ping_kernel<<<dim3(BB), dim3(256), 0, stream>>>(g_in, g_W0, g_W1, g_Wee, g_Wei, g_Wie, out, T, dA, dG);
}